// Round 1
// baseline (577.534 us; speedup 1.0000x reference)
//
#include <hip/hip_runtime.h>
#include <cstdint>
#include <cstddef>

typedef _Float16 f16;
typedef __attribute__((ext_vector_type(4))) _Float16 f16x4;
typedef __attribute__((ext_vector_type(8))) _Float16 f16x8;
typedef __attribute__((ext_vector_type(4))) float f32x4;

#define NB 2
#define SEQ 2048
#define DM 2048
#define NH 8
#define HD 256
#define MT (NB * SEQ)   // 4096

// ---------------------------------------------------------------------------
// global -> LDS direct copy, 16B per lane. LDS dest must be wave-uniform base.
__device__ __forceinline__ void gload16(const f16* g, f16* l) {
    __builtin_amdgcn_global_load_lds(
        (const __attribute__((address_space(1))) uint32_t*)(const void*)g,
        (__attribute__((address_space(3))) uint32_t*)(void*)l,
        16, 0, 0);
}

// ---------------------------------------------------------------------------
// f32 -> f16 conversion (vectorized, grid-stride)
__global__ __launch_bounds__(256) void k_cvt(const float* __restrict__ src,
                                             f16* __restrict__ dst, int n) {
    for (int i = (blockIdx.x * blockDim.x + threadIdx.x) * 4; i < n;
         i += gridDim.x * blockDim.x * 4) {
        f32x4 v = *(const f32x4*)(src + i);
        f16x4 h;
        h[0] = (f16)v[0]; h[1] = (f16)v[1]; h[2] = (f16)v[2]; h[3] = (f16)v[3];
        *(f16x4*)(dst + i) = h;
    }
}

// ---------------------------------------------------------------------------
// 128x128 tile GEMM core (m97 structure): C = A[M,K] * B[N,K]^T
// 256 threads = 4 waves in 2x2, each wave 64x64 (4x4 frags of 16x16x32 f16)
__device__ __forceinline__ void gemm128_core(const f16* __restrict__ A,
                                             const f16* __restrict__ B,
                                             int m0, int n0,
                                             f16* As, f16* Bs,
                                             f32x4 acc[4][4]) {
    const int tid  = threadIdx.x;
    const int wave = tid >> 6, lane = tid & 63;
    const int wr = (wave >> 1) << 6, wc = (wave & 1) << 6;
    const int lr = lane & 15;            // row within 16
    const int lk = (lane >> 4) << 3;     // k elem offset (0,8,16,24)

    for (int k0 = 0; k0 < DM; k0 += 32) {
        __syncthreads();
#pragma unroll
        for (int j = 0; j < 2; ++j) {
            int base = (j * 4 + wave) << 9;          // 512 elems per wave-issue
            int flat = base + (lane << 3);
            int r = flat >> 5, c = flat & 31;
            gload16(A + (size_t)(m0 + r) * DM + k0 + c, As + base);
            gload16(B + (size_t)(n0 + r) * DM + k0 + c, Bs + base);
        }
        __syncthreads();
        f16x8 af[4], bf[4];
#pragma unroll
        for (int mi = 0; mi < 4; ++mi)
            af[mi] = *(const f16x8*)&As[(wr + mi * 16 + lr) * 32 + lk];
#pragma unroll
        for (int nj = 0; nj < 4; ++nj)
            bf[nj] = *(const f16x8*)&Bs[(wc + nj * 16 + lr) * 32 + lk];
#pragma unroll
        for (int mi = 0; mi < 4; ++mi)
#pragma unroll
            for (int nj = 0; nj < 4; ++nj)
                acc[mi][nj] = __builtin_amdgcn_mfma_f32_16x16x32_f16(
                    af[mi], bf[nj], acc[mi][nj], 0, 0, 0);
    }
}

// ---------------------------------------------------------------------------
// QKV projection: y = x @ W^T + b ; Q scaled by 1/16; Q,K -> [b,h,s,d], V -> [b,h,d,s]
__global__ __launch_bounds__(256) void k_proj_qkv(
    const f16* __restrict__ xh, const f16* __restrict__ Wq,
    const f16* __restrict__ Wk, const f16* __restrict__ Wv,
    const float* __restrict__ bq, const float* __restrict__ bk,
    const float* __restrict__ bv,
    f16* __restrict__ Qh, f16* __restrict__ Kh, f16* __restrict__ Vth) {
    __shared__ __align__(16) f16 As[128 * 32];
    __shared__ __align__(16) f16 Bs[128 * 32];
    const int mode = blockIdx.z;
    const f16* W = (mode == 0) ? Wq : (mode == 1) ? Wk : Wv;
    const float* bias = (mode == 0) ? bq : (mode == 1) ? bk : bv;

    const int m0 = blockIdx.y * 128, n0 = blockIdx.x * 128;
    f32x4 acc[4][4];
#pragma unroll
    for (int mi = 0; mi < 4; ++mi)
#pragma unroll
        for (int nj = 0; nj < 4; ++nj) acc[mi][nj] = (f32x4){0.f, 0.f, 0.f, 0.f};

    gemm128_core(xh, W, m0, n0, As, Bs, acc);

    const int lane = threadIdx.x & 63, wave = threadIdx.x >> 6;
    const int wr = (wave >> 1) << 6, wc = (wave & 1) << 6;
    const int lr = lane & 15, lg = lane >> 4;
#pragma unroll
    for (int nj = 0; nj < 4; ++nj) {
        int n = n0 + wc + nj * 16 + lr;
        float bb = bias[n];
        int h = n >> 8, d = n & 255;
#pragma unroll
        for (int mi = 0; mi < 4; ++mi) {
#pragma unroll
            for (int i = 0; i < 4; ++i) {
                int m = m0 + wr + mi * 16 + lg * 4 + i;
                int b = m >> 11, s = m & 2047;
                float v = acc[mi][nj][i] + bb;
                size_t bh = (size_t)(b * NH + h);
                if (mode == 0)
                    Qh[((bh * SEQ + s) << 8) + d] = (f16)(v * 0.0625f);
                else if (mode == 1)
                    Kh[((bh * SEQ + s) << 8) + d] = (f16)v;
                else
                    Vth[((bh * HD + d) << 11) + s] = (f16)v;
            }
        }
    }
}

// ---------------------------------------------------------------------------
// Output projection: out = O @ Wo^T + bo  (f32 out)
__global__ __launch_bounds__(256) void k_proj_o(
    const f16* __restrict__ Oh, const f16* __restrict__ Wo,
    const float* __restrict__ bo, float* __restrict__ out) {
    __shared__ __align__(16) f16 As[128 * 32];
    __shared__ __align__(16) f16 Bs[128 * 32];
    const int m0 = blockIdx.y * 128, n0 = blockIdx.x * 128;
    f32x4 acc[4][4];
#pragma unroll
    for (int mi = 0; mi < 4; ++mi)
#pragma unroll
        for (int nj = 0; nj < 4; ++nj) acc[mi][nj] = (f32x4){0.f, 0.f, 0.f, 0.f};

    gemm128_core(Oh, Wo, m0, n0, As, Bs, acc);

    const int lane = threadIdx.x & 63, wave = threadIdx.x >> 6;
    const int wr = (wave >> 1) << 6, wc = (wave & 1) << 6;
    const int lr = lane & 15, lg = lane >> 4;
#pragma unroll
    for (int nj = 0; nj < 4; ++nj) {
        int n = n0 + wc + nj * 16 + lr;
        float bb = bo[n];
#pragma unroll
        for (int mi = 0; mi < 4; ++mi) {
#pragma unroll
            for (int i = 0; i < 4; ++i) {
                int m = m0 + wr + mi * 16 + lg * 4 + i;
                out[(size_t)m * DM + n] = acc[mi][nj][i] + bb;
            }
        }
    }
}

// ---------------------------------------------------------------------------
// Fused causal attention. Block = (b, h, 64-row q tile), 4 waves x 16 q-rows.
// Pass A: row max/sum (streaming K tiles). Pass B: recompute S, write P (f32),
// P->LDS->frag, O += P*V. Also zero-fills the masked upper region of P.
__global__ __launch_bounds__(256, 2) void k_attn(
    const f16* __restrict__ Qh, const f16* __restrict__ Kh,
    const f16* __restrict__ Vth, float* __restrict__ P,
    f16* __restrict__ Oh) {
    __shared__ __align__(16) f16 Kl[64 * 256];     // [k-row][d]   32KB
    __shared__ __align__(16) f16 Vl[256 * 64];     // [d][k-row]   32KB
    __shared__ __align__(16) f16 Ps[4][16][80];    // per-wave P tile (padded)

    const int qb = blockIdx.x, h = blockIdx.y, b = blockIdx.z;
    const int q0 = qb * 64;
    const int tid = threadIdx.x, wave = tid >> 6, lane = tid & 63;
    const int lr = lane & 15, lg = lane >> 4;
    const size_t bh = (size_t)(b * NH + h);
    const f16* Qb = Qh + (bh << 19);
    const f16* Kb = Kh + (bh << 19);
    const f16* Vb = Vth + (bh << 19);
    float* Pb = P + (bh << 22);

    // Q fragments in registers (16 q-rows x 256 d per wave)
    f16x8 aq[8];
    {
        const f16* qrow = Qb + (size_t)(q0 + wave * 16 + lr) * HD + lg * 8;
#pragma unroll
        for (int kk = 0; kk < 8; ++kk) aq[kk] = *(const f16x8*)(qrow + kk * 32);
    }

    const int rowb = q0 + wave * 16 + lg * 4;  // +i gives absolute q row
    float m_[4], l_[4];
#pragma unroll
    for (int i = 0; i < 4; ++i) { m_[i] = -3e38f; l_[i] = 0.f; }

    // ---------------- PASS A: softmax stats ----------------
    for (int kt = 0; kt <= qb; ++kt) {
        __syncthreads();
#pragma unroll
        for (int j = 0; j < 8; ++j) {
            int base = (j * 4 + wave) << 9;
            int flat = base + (lane << 3);
            int r = flat >> 8, c = flat & 255;
            gload16(Kb + (size_t)(kt * 64 + r) * HD + c, Kl + base);
        }
        __syncthreads();
        f32x4 s[4];
#pragma unroll
        for (int nj = 0; nj < 4; ++nj) s[nj] = (f32x4){0.f, 0.f, 0.f, 0.f};
#pragma unroll
        for (int kk = 0; kk < 8; ++kk) {
#pragma unroll
            for (int nj = 0; nj < 4; ++nj) {
                f16x8 bk = *(const f16x8*)&Kl[(nj * 16 + lr) * 256 + kk * 32 + lg * 8];
                s[nj] = __builtin_amdgcn_mfma_f32_16x16x32_f16(aq[kk], bk, s[nj], 0, 0, 0);
            }
        }
        const int colb = kt * 64 + lr;
#pragma unroll
        for (int i = 0; i < 4; ++i) {
            int row = rowb + i;
            float mx = -3e38f;
#pragma unroll
            for (int nj = 0; nj < 4; ++nj) {
                float v = (colb + nj * 16 <= row) ? s[nj][i] : -3e38f;
                mx = fmaxf(mx, v);
            }
            mx = fmaxf(mx, __shfl_xor(mx, 1));
            mx = fmaxf(mx, __shfl_xor(mx, 2));
            mx = fmaxf(mx, __shfl_xor(mx, 4));
            mx = fmaxf(mx, __shfl_xor(mx, 8));
            float mn = fmaxf(m_[i], mx);
            float sum = 0.f;
#pragma unroll
            for (int nj = 0; nj < 4; ++nj)
                sum += (colb + nj * 16 <= row) ? __expf(s[nj][i] - mn) : 0.f;
            sum += __shfl_xor(sum, 1);
            sum += __shfl_xor(sum, 2);
            sum += __shfl_xor(sum, 4);
            sum += __shfl_xor(sum, 8);
            l_[i] = l_[i] * __expf(m_[i] - mn) + sum;
            m_[i] = mn;
        }
    }

    float inv[4];
#pragma unroll
    for (int i = 0; i < 4; ++i) inv[i] = 1.f / l_[i];

    f32x4 o[16];
#pragma unroll
    for (int n = 0; n < 16; ++n) o[n] = (f32x4){0.f, 0.f, 0.f, 0.f};

    // ---------------- PASS B: P write + O accumulate ----------------
    for (int kt = 0; kt <= qb; ++kt) {
        __syncthreads();
#pragma unroll
        for (int j = 0; j < 8; ++j) {
            int base = (j * 4 + wave) << 9;
            int flat = base + (lane << 3);
            int rk = flat >> 8, ck = flat & 255;
            gload16(Kb + (size_t)(kt * 64 + rk) * HD + ck, Kl + base);
            int rv = flat >> 6, cv = flat & 63;
            gload16(Vb + ((size_t)rv << 11) + kt * 64 + cv, Vl + base);
        }
        __syncthreads();
        f32x4 s[4];
#pragma unroll
        for (int nj = 0; nj < 4; ++nj) s[nj] = (f32x4){0.f, 0.f, 0.f, 0.f};
#pragma unroll
        for (int kk = 0; kk < 8; ++kk) {
#pragma unroll
            for (int nj = 0; nj < 4; ++nj) {
                f16x8 bk = *(const f16x8*)&Kl[(nj * 16 + lr) * 256 + kk * 32 + lg * 8];
                s[nj] = __builtin_amdgcn_mfma_f32_16x16x32_f16(aq[kk], bk, s[nj], 0, 0, 0);
            }
        }
#pragma unroll
        for (int i = 0; i < 4; ++i) {
            int row = rowb + i;
#pragma unroll
            for (int nj = 0; nj < 4; ++nj) {
                int col = kt * 64 + nj * 16 + lr;
                float p = (col <= row) ? __expf(s[nj][i] - m_[i]) * inv[i] : 0.f;
                Pb[(size_t)row * SEQ + col] = p;
                Ps[wave][lg * 4 + i][nj * 16 + lr] = (f16)p;
            }
        }
#pragma unroll
        for (int kk2 = 0; kk2 < 2; ++kk2) {
            f16x8 pa = *(const f16x8*)&Ps[wave][lr][kk2 * 32 + lg * 8];
#pragma unroll
            for (int n = 0; n < 16; ++n) {
                f16x8 bv = *(const f16x8*)&Vl[(n * 16 + lr) * 64 + kk2 * 32 + lg * 8];
                o[n] = __builtin_amdgcn_mfma_f32_16x16x32_f16(pa, bv, o[n], 0, 0, 0);
            }
        }
    }

    // zero-fill strictly-masked P region for these 64 q rows
    int kstart = (qb + 1) * 64;
    if (kstart < SEQ) {
        f32x4 z = (f32x4){0.f, 0.f, 0.f, 0.f};
        for (int r = 0; r < 64; ++r) {
            float* rp = Pb + (size_t)(q0 + r) * SEQ;
            for (int c = kstart + tid * 4; c < SEQ; c += 1024)
                *(f32x4*)(rp + c) = z;
        }
    }

    // write O (f16) to [b, s, h*HD + d]
#pragma unroll
    for (int n = 0; n < 16; ++n) {
#pragma unroll
        for (int i = 0; i < 4; ++i) {
            int row = rowb + i;
            int d = n * 16 + lr;
            Oh[((size_t)b * SEQ + row) * DM + h * HD + d] = (f16)o[n][i];
        }
    }
}

// ---------------------------------------------------------------------------
extern "C" void kernel_launch(void* const* d_in, const int* in_sizes, int n_in,
                              void* d_out, int out_size, void* d_ws, size_t ws_size,
                              hipStream_t stream) {
    const float* x  = (const float*)d_in[0];
    const float* Wq = (const float*)d_in[1];
    const float* bq = (const float*)d_in[2];
    const float* Wk = (const float*)d_in[3];
    const float* bk = (const float*)d_in[4];
    const float* Wv = (const float*)d_in[5];
    const float* bv = (const float*)d_in[6];
    const float* Wo = (const float*)d_in[7];
    const float* bo = (const float*)d_in[8];

    float* out  = (float*)d_out;
    float* Pout = out + (size_t)MT * DM;          // attn_probs region (256MB)

    // f16 scratch for x and Wq/Wk/Wv parked inside the (not yet written) P
    // region of d_out; they are dead before k_attn overwrites that region.
    f16* xh  = (f16*)Pout;                         // 8388608 f16
    f16* Wqh = xh + (size_t)MT * DM;               // 4194304 f16 each
    f16* Wkh = Wqh + (size_t)DM * DM;
    f16* Wvh = Wkh + (size_t)DM * DM;

    // persistent f16 scratch in ws (must survive into/through k_attn)
    f16* ws16 = (f16*)d_ws;
    f16* Woh = ws16;                               // 4194304
    f16* Qh  = Woh + (size_t)DM * DM;              // 8388608
    f16* Kh  = Qh + (size_t)MT * DM / 2 * 2;       // [b,h,s,d] = 8388608
    f16* Vth = Kh + (size_t)8388608;               // [b,h,d,s] = 8388608
    f16* Oh  = Vth + (size_t)8388608;              // [b,s,D]   = 8388608
    if (ws_size < (size_t)(4194304 + 4 * 8388608) * sizeof(f16)) return;

    // conversions
    k_cvt<<<2048, 256, 0, stream>>>(x, xh, MT * DM);
    k_cvt<<<1024, 256, 0, stream>>>(Wq, Wqh, DM * DM);
    k_cvt<<<1024, 256, 0, stream>>>(Wk, Wkh, DM * DM);
    k_cvt<<<1024, 256, 0, stream>>>(Wv, Wvh, DM * DM);
    k_cvt<<<1024, 256, 0, stream>>>(Wo, Woh, DM * DM);

    // QKV projections
    dim3 g1(DM / 128, MT / 128, 3);
    k_proj_qkv<<<g1, 256, 0, stream>>>(xh, Wqh, Wkh, Wvh, bq, bk, bv, Qh, Kh, Vth);

    // fused causal attention + P materialization
    dim3 g2(SEQ / 64, NH, NB);
    k_attn<<<g2, 256, 0, stream>>>(Qh, Kh, Vth, Pout, Oh);

    // output projection
    dim3 g3(DM / 128, MT / 128, 1);
    k_proj_o<<<g3, 256, 0, stream>>>(Oh, Woh, bo, out);
}

// Round 2
// 410.406 us; speedup vs baseline: 1.4072x; 1.4072x over previous
//
#include <hip/hip_runtime.h>
#include <cstdint>
#include <cstddef>

typedef _Float16 f16;
typedef __attribute__((ext_vector_type(4))) _Float16 f16x4;
typedef __attribute__((ext_vector_type(8))) _Float16 f16x8;
typedef __attribute__((ext_vector_type(4))) float f32x4;

#define NB 2
#define SEQ 2048
#define DM 2048
#define NH 8
#define HD 256
#define MT (NB * SEQ)   // 4096

// ---------------------------------------------------------------------------
// global -> LDS direct copy, 16B per lane. LDS dest must be wave-uniform base.
__device__ __forceinline__ void gload16(const f16* g, f16* l) {
    __builtin_amdgcn_global_load_lds(
        (const __attribute__((address_space(1))) uint32_t*)(const void*)g,
        (__attribute__((address_space(3))) uint32_t*)(void*)l,
        16, 0, 0);
}

// ---------------------------------------------------------------------------
// f32 -> f16 conversion (vectorized, grid-stride)
__global__ __launch_bounds__(256) void k_cvt(const float* __restrict__ src,
                                             f16* __restrict__ dst, int n) {
    for (int i = (blockIdx.x * blockDim.x + threadIdx.x) * 4; i < n;
         i += gridDim.x * blockDim.x * 4) {
        f32x4 v = *(const f32x4*)(src + i);
        f16x4 h;
        h[0] = (f16)v[0]; h[1] = (f16)v[1]; h[2] = (f16)v[2]; h[3] = (f16)v[3];
        *(f16x4*)(dst + i) = h;
    }
}

// ---------------------------------------------------------------------------
// 128x128 tile GEMM core (m97 structure): C = A[M,K] * B[N,K]^T
__device__ __forceinline__ void gemm128_core(const f16* __restrict__ A,
                                             const f16* __restrict__ B,
                                             int m0, int n0,
                                             f16* As, f16* Bs,
                                             f32x4 acc[4][4]) {
    const int tid  = threadIdx.x;
    const int wave = tid >> 6, lane = tid & 63;
    const int wr = (wave >> 1) << 6, wc = (wave & 1) << 6;
    const int lr = lane & 15;            // row within 16
    const int lk = (lane >> 4) << 3;     // k elem offset (0,8,16,24)

    for (int k0 = 0; k0 < DM; k0 += 32) {
        __syncthreads();
#pragma unroll
        for (int j = 0; j < 2; ++j) {
            int base = (j * 4 + wave) << 9;          // 512 elems per wave-issue
            int flat = base + (lane << 3);
            int r = flat >> 5, c = flat & 31;
            gload16(A + (size_t)(m0 + r) * DM + k0 + c, As + base);
            gload16(B + (size_t)(n0 + r) * DM + k0 + c, Bs + base);
        }
        __syncthreads();
        f16x8 af[4], bf[4];
#pragma unroll
        for (int mi = 0; mi < 4; ++mi)
            af[mi] = *(const f16x8*)&As[(wr + mi * 16 + lr) * 32 + lk];
#pragma unroll
        for (int nj = 0; nj < 4; ++nj)
            bf[nj] = *(const f16x8*)&Bs[(wc + nj * 16 + lr) * 32 + lk];
        __builtin_amdgcn_s_setprio(1);
#pragma unroll
        for (int mi = 0; mi < 4; ++mi)
#pragma unroll
            for (int nj = 0; nj < 4; ++nj)
                acc[mi][nj] = __builtin_amdgcn_mfma_f32_16x16x32_f16(
                    af[mi], bf[nj], acc[mi][nj], 0, 0, 0);
        __builtin_amdgcn_s_setprio(0);
    }
}

// ---------------------------------------------------------------------------
// QKV projection: y = x @ W^T + b ; Q scaled by 1/16; Q,K -> [b,h,s,d], V -> [b,h,d,s]
__global__ __launch_bounds__(256) void k_proj_qkv(
    const f16* __restrict__ xh, const f16* __restrict__ Wq,
    const f16* __restrict__ Wk, const f16* __restrict__ Wv,
    const float* __restrict__ bq, const float* __restrict__ bk,
    const float* __restrict__ bv,
    f16* __restrict__ Qh, f16* __restrict__ Kh, f16* __restrict__ Vth) {
    __shared__ __align__(16) f16 As[128 * 32];
    __shared__ __align__(16) f16 Bs[128 * 32];
    const int mode = blockIdx.z;
    const f16* W = (mode == 0) ? Wq : (mode == 1) ? Wk : Wv;
    const float* bias = (mode == 0) ? bq : (mode == 1) ? bk : bv;

    const int m0 = blockIdx.y * 128, n0 = blockIdx.x * 128;
    f32x4 acc[4][4];
#pragma unroll
    for (int mi = 0; mi < 4; ++mi)
#pragma unroll
        for (int nj = 0; nj < 4; ++nj) acc[mi][nj] = (f32x4){0.f, 0.f, 0.f, 0.f};

    gemm128_core(xh, W, m0, n0, As, Bs, acc);

    const int lane = threadIdx.x & 63, wave = threadIdx.x >> 6;
    const int wr = (wave >> 1) << 6, wc = (wave & 1) << 6;
    const int lr = lane & 15, lg = lane >> 4;
#pragma unroll
    for (int nj = 0; nj < 4; ++nj) {
        int n = n0 + wc + nj * 16 + lr;
        float bb = bias[n];
        int h = n >> 8, d = n & 255;
#pragma unroll
        for (int mi = 0; mi < 4; ++mi) {
#pragma unroll
            for (int i = 0; i < 4; ++i) {
                int m = m0 + wr + mi * 16 + lg * 4 + i;
                int b = m >> 11, s = m & 2047;
                float v = acc[mi][nj][i] + bb;
                size_t bh = (size_t)(b * NH + h);
                if (mode == 0)
                    Qh[((bh * SEQ + s) << 8) + d] = (f16)(v * 0.0625f);
                else if (mode == 1)
                    Kh[((bh * SEQ + s) << 8) + d] = (f16)v;
                else
                    Vth[((bh * HD + d) << 11) + s] = (f16)v;
            }
        }
    }
}

// ---------------------------------------------------------------------------
// Output projection: out = O @ Wo^T + bo  (f32 out)
__global__ __launch_bounds__(256) void k_proj_o(
    const f16* __restrict__ Oh, const f16* __restrict__ Wo,
    const float* __restrict__ bo, float* __restrict__ out) {
    __shared__ __align__(16) f16 As[128 * 32];
    __shared__ __align__(16) f16 Bs[128 * 32];
    const int m0 = blockIdx.y * 128, n0 = blockIdx.x * 128;
    f32x4 acc[4][4];
#pragma unroll
    for (int mi = 0; mi < 4; ++mi)
#pragma unroll
        for (int nj = 0; nj < 4; ++nj) acc[mi][nj] = (f32x4){0.f, 0.f, 0.f, 0.f};

    gemm128_core(Oh, Wo, m0, n0, As, Bs, acc);

    const int lane = threadIdx.x & 63, wave = threadIdx.x >> 6;
    const int wr = (wave >> 1) << 6, wc = (wave & 1) << 6;
    const int lr = lane & 15, lg = lane >> 4;
#pragma unroll
    for (int nj = 0; nj < 4; ++nj) {
        int n = n0 + wc + nj * 16 + lr;
        float bb = bo[n];
#pragma unroll
        for (int mi = 0; mi < 4; ++mi) {
#pragma unroll
            for (int i = 0; i < 4; ++i) {
                int m = m0 + wr + mi * 16 + lg * 4 + i;
                out[(size_t)m * DM + n] = acc[mi][nj][i] + bb;
            }
        }
    }
}

// ---------------------------------------------------------------------------
// Fused causal attention. 1D grid of 512 blocks; co-resident pairs (L, L+256)
// get complementary qb so per-CU work is ~constant; heavy blocks first.
// 4 waves x 16 q-rows. Pass A: row max/sum. Pass B: recompute S, write P
// (wide f32 stores from LDS), O += P*V.
// Kl/Vl are XOR-swizzled (elem ^= (row&7)<<3) — staged via pre-swizzled global
// source (global_load_lds writes linearly), read with the same XOR.
__global__ __launch_bounds__(256, 2) void k_attn(
    const f16* __restrict__ Qh, const f16* __restrict__ Kh,
    const f16* __restrict__ Vth, float* __restrict__ P,
    f16* __restrict__ Oh) {
    __shared__ __align__(16) f16 Kl[64 * 256];     // [k-row][d] swizzled, 32KB
    __shared__ __align__(16) f16 Vl[256 * 64];     // [d][k-row] swizzled, 32KB
    __shared__ __align__(16) f16 Ps[4][16][72];    // per-wave P tile (pad 8)

    const int L = blockIdx.x;
    const int half = L >> 8, p = L & 255;
    const int h = p >> 5;
    const int qb = half ? (p & 31) : (31 - (p & 31));
    const int b = half;

    const int q0 = qb * 64;
    const int tid = threadIdx.x, wave = tid >> 6, lane = tid & 63;
    const int lr = lane & 15, lg = lane >> 4;
    const size_t bh = (size_t)(b * NH + h);
    const f16* Qb = Qh + (bh << 19);
    const f16* Kb = Kh + (bh << 19);
    const f16* Vb = Vth + (bh << 19);
    float* Pb = P + (bh << 22);

    const int swz = (lr & 7) << 3;   // read-side XOR (elem units)

    // Q fragments in registers (16 q-rows x 256 d per wave)
    f16x8 aq[8];
    {
        const f16* qrow = Qb + (size_t)(q0 + wave * 16 + lr) * HD + lg * 8;
#pragma unroll
        for (int kk = 0; kk < 8; ++kk) aq[kk] = *(const f16x8*)(qrow + kk * 32);
    }

    const int rowb = q0 + wave * 16 + lg * 4;  // +i gives absolute q row
    float m_[4], l_[4];
#pragma unroll
    for (int i = 0; i < 4; ++i) { m_[i] = -3e38f; l_[i] = 0.f; }

    // ---------------- PASS A: softmax stats ----------------
    for (int kt = 0; kt <= qb; ++kt) {
        __syncthreads();
#pragma unroll
        for (int j = 0; j < 8; ++j) {
            int base = (j * 4 + wave) << 9;
            int flat = base + (lane << 3);
            int r = flat >> 8;
            int c = (flat & 255) ^ ((r & 7) << 3);   // inverse-swizzled source
            gload16(Kb + (size_t)(kt * 64 + r) * HD + c, Kl + base);
        }
        __syncthreads();
        f32x4 s[4];
#pragma unroll
        for (int nj = 0; nj < 4; ++nj) s[nj] = (f32x4){0.f, 0.f, 0.f, 0.f};
        __builtin_amdgcn_s_setprio(1);
#pragma unroll
        for (int kk = 0; kk < 8; ++kk) {
#pragma unroll
            for (int nj = 0; nj < 4; ++nj) {
                f16x8 bk = *(const f16x8*)&Kl[(nj * 16 + lr) * 256 +
                                              ((kk * 32 + lg * 8) ^ swz)];
                s[nj] = __builtin_amdgcn_mfma_f32_16x16x32_f16(aq[kk], bk, s[nj], 0, 0, 0);
            }
        }
        __builtin_amdgcn_s_setprio(0);
        const int colb = kt * 64 + lr;
#pragma unroll
        for (int i = 0; i < 4; ++i) {
            int row = rowb + i;
            float mx = -3e38f;
#pragma unroll
            for (int nj = 0; nj < 4; ++nj) {
                float v = (colb + nj * 16 <= row) ? s[nj][i] : -3e38f;
                mx = fmaxf(mx, v);
            }
            mx = fmaxf(mx, __shfl_xor(mx, 1));
            mx = fmaxf(mx, __shfl_xor(mx, 2));
            mx = fmaxf(mx, __shfl_xor(mx, 4));
            mx = fmaxf(mx, __shfl_xor(mx, 8));
            float mn = fmaxf(m_[i], mx);
            float sum = 0.f;
#pragma unroll
            for (int nj = 0; nj < 4; ++nj)
                sum += (colb + nj * 16 <= row) ? __expf(s[nj][i] - mn) : 0.f;
            sum += __shfl_xor(sum, 1);
            sum += __shfl_xor(sum, 2);
            sum += __shfl_xor(sum, 4);
            sum += __shfl_xor(sum, 8);
            l_[i] = l_[i] * __expf(m_[i] - mn) + sum;
            m_[i] = mn;
        }
    }

    float inv[4];
#pragma unroll
    for (int i = 0; i < 4; ++i) inv[i] = 1.f / l_[i];

    f32x4 o[16];
#pragma unroll
    for (int n = 0; n < 16; ++n) o[n] = (f32x4){0.f, 0.f, 0.f, 0.f};

    // ---------------- PASS B: P write + O accumulate ----------------
    for (int kt = 0; kt <= qb; ++kt) {
        __syncthreads();
#pragma unroll
        for (int j = 0; j < 8; ++j) {
            int base = (j * 4 + wave) << 9;
            int flat = base + (lane << 3);
            int rk = flat >> 8;
            int ck = (flat & 255) ^ ((rk & 7) << 3);
            gload16(Kb + (size_t)(kt * 64 + rk) * HD + ck, Kl + base);
            int rv = flat >> 6;
            int cv = (flat & 63) ^ ((rv & 7) << 3);
            gload16(Vb + ((size_t)rv << 11) + kt * 64 + cv, Vl + base);
        }
        __syncthreads();
        f32x4 s[4];
#pragma unroll
        for (int nj = 0; nj < 4; ++nj) s[nj] = (f32x4){0.f, 0.f, 0.f, 0.f};
        __builtin_amdgcn_s_setprio(1);
#pragma unroll
        for (int kk = 0; kk < 8; ++kk) {
#pragma unroll
            for (int nj = 0; nj < 4; ++nj) {
                f16x8 bk = *(const f16x8*)&Kl[(nj * 16 + lr) * 256 +
                                              ((kk * 32 + lg * 8) ^ swz)];
                s[nj] = __builtin_amdgcn_mfma_f32_16x16x32_f16(aq[kk], bk, s[nj], 0, 0, 0);
            }
        }
        __builtin_amdgcn_s_setprio(0);
#pragma unroll
        for (int i = 0; i < 4; ++i) {
            int row = rowb + i;
#pragma unroll
            for (int nj = 0; nj < 4; ++nj) {
                int col = kt * 64 + nj * 16 + lr;
                float pv = (col <= row) ? __expf(s[nj][i] - m_[i]) * inv[i] : 0.f;
                Ps[wave][lg * 4 + i][nj * 16 + lr] = (f16)pv;
            }
        }
        // wide P store: wave writes its 16 rows x 64 cols from Ps (f16->f32)
#pragma unroll
        for (int h2 = 0; h2 < 2; ++h2) {
            int rr = h2 * 8 + (lane >> 3);
            int cc = (lane & 7) * 8;
            f16x8 ph = *(const f16x8*)&Ps[wave][rr][cc];
            int row = q0 + wave * 16 + rr;
            float* dst = Pb + (size_t)row * SEQ + kt * 64 + cc;
            f32x4 lo = {(float)ph[0], (float)ph[1], (float)ph[2], (float)ph[3]};
            f32x4 hi = {(float)ph[4], (float)ph[5], (float)ph[6], (float)ph[7]};
            *(f32x4*)dst = lo;
            *(f32x4*)(dst + 4) = hi;
        }
        // PV accumulate
        __builtin_amdgcn_s_setprio(1);
#pragma unroll
        for (int kk2 = 0; kk2 < 2; ++kk2) {
            f16x8 pa = *(const f16x8*)&Ps[wave][lr][kk2 * 32 + lg * 8];
#pragma unroll
            for (int n = 0; n < 16; ++n) {
                f16x8 bv = *(const f16x8*)&Vl[(n * 16 + lr) * 64 +
                                              ((kk2 * 32 + lg * 8) ^ swz)];
                o[n] = __builtin_amdgcn_mfma_f32_16x16x32_f16(pa, bv, o[n], 0, 0, 0);
            }
        }
        __builtin_amdgcn_s_setprio(0);
    }

    // zero-fill strictly-masked P region for these 64 q rows
    int kstart = (qb + 1) * 64;
    if (kstart < SEQ) {
        f32x4 z = (f32x4){0.f, 0.f, 0.f, 0.f};
        for (int r = 0; r < 64; ++r) {
            float* rp = Pb + (size_t)(q0 + r) * SEQ;
            for (int c = kstart + tid * 4; c < SEQ; c += 1024)
                *(f32x4*)(rp + c) = z;
        }
    }

    // write O (f16) to [b, s, h*HD + d]
#pragma unroll
    for (int n = 0; n < 16; ++n) {
#pragma unroll
        for (int i = 0; i < 4; ++i) {
            int row = rowb + i;
            int d = n * 16 + lr;
            Oh[((size_t)b * SEQ + row) * DM + h * HD + d] = (f16)o[n][i];
        }
    }
}

// ---------------------------------------------------------------------------
extern "C" void kernel_launch(void* const* d_in, const int* in_sizes, int n_in,
                              void* d_out, int out_size, void* d_ws, size_t ws_size,
                              hipStream_t stream) {
    const float* x  = (const float*)d_in[0];
    const float* Wq = (const float*)d_in[1];
    const float* bq = (const float*)d_in[2];
    const float* Wk = (const float*)d_in[3];
    const float* bk = (const float*)d_in[4];
    const float* Wv = (const float*)d_in[5];
    const float* bv = (const float*)d_in[6];
    const float* Wo = (const float*)d_in[7];
    const float* bo = (const float*)d_in[8];

    float* out  = (float*)d_out;
    float* Pout = out + (size_t)MT * DM;          // attn_probs region (256MB)

    // f16 scratch for x and Wq/Wk/Wv parked inside the (not yet written) P
    // region of d_out; they are dead before k_attn overwrites that region.
    f16* xh  = (f16*)Pout;                         // 8388608 f16
    f16* Wqh = xh + (size_t)MT * DM;               // 4194304 f16 each
    f16* Wkh = Wqh + (size_t)DM * DM;
    f16* Wvh = Wkh + (size_t)DM * DM;

    // persistent f16 scratch in ws (must survive into/through k_attn)
    f16* ws16 = (f16*)d_ws;
    f16* Woh = ws16;                               // 4194304
    f16* Qh  = Woh + (size_t)DM * DM;              // 8388608
    f16* Kh  = Qh + (size_t)8388608;               // [b,h,s,d] = 8388608
    f16* Vth = Kh + (size_t)8388608;               // [b,h,d,s] = 8388608
    f16* Oh  = Vth + (size_t)8388608;              // [b,s,D]   = 8388608
    if (ws_size < (size_t)(4194304 + 4 * 8388608) * sizeof(f16)) return;

    // conversions
    k_cvt<<<2048, 256, 0, stream>>>(x, xh, MT * DM);
    k_cvt<<<1024, 256, 0, stream>>>(Wq, Wqh, DM * DM);
    k_cvt<<<1024, 256, 0, stream>>>(Wk, Wkh, DM * DM);
    k_cvt<<<1024, 256, 0, stream>>>(Wv, Wvh, DM * DM);
    k_cvt<<<1024, 256, 0, stream>>>(Wo, Woh, DM * DM);

    // QKV projections
    dim3 g1(DM / 128, MT / 128, 3);
    k_proj_qkv<<<g1, 256, 0, stream>>>(xh, Wqh, Wkh, Wvh, bq, bk, bv, Qh, Kh, Vth);

    // fused causal attention + P materialization (1D balanced grid)
    k_attn<<<dim3(512), 256, 0, stream>>>(Qh, Kh, Vth, Pout, Oh);

    // output projection
    dim3 g3(DM / 128, MT / 128, 1);
    k_proj_o<<<g3, 256, 0, stream>>>(Oh, Woh, bo, out);
}